// Round 5
// baseline (182.312 us; speedup 1.0000x reference)
//
#include <hip/hip_runtime.h>
#include <hip/hip_bf16.h>
#include <math.h>

// SAGAN self-attention, B=4, H=W=64, C=256, Ck=32, N=4096 (16384 total rows).
//   prep_wtf : WTf fragment-contiguous repack of [Wf|Wg|Wh]^T (bf16), coalesced.
//   proj_mfma: 64-row blocks, 8 role-split waves -> f,g bf16 [B*N,32], hT bf16 [B,256,4096].
//   attn     : flash attention, Q-tile 64, 8 waves uneven d-split (S-waves 16d, others 48d),
//              S computed transposed, P transposed IN REGISTERS via cvt_pk + permlane swaps,
//              P shared through fragment-linear LDS (b128, zero-conflict),
//              f/H global->reg ping-pong prefetch, exp shift folded into MFMA C-init.
//
// MFMA 16x16x32 lane layouts (verified m89):
//   A[row][k]: row = lane&15, k = (lane>>4)*8 + j
//   B[k][col]: col = lane&15, k = (lane>>4)*8 + j
//   D[row][col]: col = lane&15, row = (lane>>4)*4 + reg

typedef __bf16 bf16x8 __attribute__((ext_vector_type(8)));
typedef float f32x4 __attribute__((ext_vector_type(4)));

#define NPIX 4096
#define CDIM 256
#define CK   32

union U128 { unsigned int d[4]; uint4 u4; bf16x8 v; };

__device__ __forceinline__ unsigned int cvtpk(float lo, float hi) {
    unsigned int r;
    asm("v_cvt_pk_bf16_f32 %0, %1, %2" : "=v"(r) : "v"(lo), "v"(hi));
    return r;
}

// WTf layout: [ct 0..19][kk 0..7][l15 0..15][32]; channel = ct*16+l15, k = kk*32+j.
__global__ __launch_bounds__(256) void prep_wtf(
    const float* __restrict__ Wf, const float* __restrict__ Wg,
    const float* __restrict__ Wh, __bf16* __restrict__ WTf)
{
    const int k = blockIdx.x;     // 0..255
    const int c = threadIdx.x;    // 0..255
    const int kk = k >> 5, kj = k & 31;
    // h channels (coalesced read of Wh row k)
    {
        const float v = Wh[k * 256 + c];
        const int ct = 4 + (c >> 4), l15 = c & 15;
        WTf[((size_t)(ct * 8 + kk) * 16 + l15) * 32 + kj] = (__bf16)v;
    }
    if (c < 32) {
        const float v = Wf[k * 32 + c];
        const int ct = c >> 4, l15 = c & 15;
        WTf[((size_t)(ct * 8 + kk) * 16 + l15) * 32 + kj] = (__bf16)v;
    } else if (c < 64) {
        const int cc = c - 32;
        const float v = Wg[k * 32 + cc];
        const int ct = 2 + (cc >> 4), l15 = cc & 15;
        WTf[((size_t)(ct * 8 + kk) * 16 + l15) * 32 + kj] = (__bf16)v;
    }
}

__global__ __launch_bounds__(512, 1) void proj_mfma(
    const float* __restrict__ x, const __bf16* __restrict__ WTf,
    const float* __restrict__ bf_, const float* __restrict__ bg_,
    const float* __restrict__ bh_,
    __bf16* __restrict__ fbuf, __bf16* __restrict__ gbuf,
    __bf16* __restrict__ hT)
{
    // xs: [64 rows][256 k] bf16, 16B-slot XOR swizzle (slot ^= row&7)
    __shared__ __bf16 xs[64 * 256];

    const int t = threadIdx.x;
    const int rowbase = blockIdx.x * 64;   // grid 256

    #pragma unroll
    for (int i = 0; i < 8; ++i) {
        const int flat = i * 2048 + t * 4;
        const int row = flat >> 8, col = flat & 255;
        const float4 xv = *(const float4*)&x[(size_t)rowbase * 256 + flat];
        const unsigned int d0 = cvtpk(xv.x, xv.y);
        const unsigned int d1 = cvtpk(xv.z, xv.w);
        const int s = (col >> 3) ^ (row & 7);
        uint2 w; w.x = d0; w.y = d1;
        *(uint2*)&xs[row * 256 + s * 8 + (col & 7)] = w;
    }
    __syncthreads();

    const int wv = t >> 6, lane = t & 63, l15 = lane & 15, lhi = lane >> 4;
    const int b = rowbase >> 12;
    const int nloc = rowbase & 4095;

    if (wv < 2) {
        // f,g for rows rb0*16 .. +32
        const int rb0 = wv * 2;
        f32x4 acc[4][2];
        #pragma unroll
        for (int c = 0; c < 4; ++c)
            #pragma unroll
            for (int rb = 0; rb < 2; ++rb) acc[c][rb] = (f32x4){0.f, 0.f, 0.f, 0.f};
        #pragma unroll
        for (int kk = 0; kk < 8; ++kk) {
            bf16x8 xf[2];
            #pragma unroll
            for (int rb = 0; rb < 2; ++rb) {
                const int row = (rb0 + rb) * 16 + l15;
                xf[rb] = *(const bf16x8*)&xs[row * 256 + (((kk * 4 + lhi) ^ (row & 7)) * 8)];
            }
            #pragma unroll
            for (int c = 0; c < 4; ++c) {
                const bf16x8 w = *(const bf16x8*)&WTf[((size_t)(c * 8 + kk) * 16 + l15) * 32 + lhi * 8];
                acc[c][0] = __builtin_amdgcn_mfma_f32_16x16x32_bf16(xf[0], w, acc[c][0], 0, 0, 0);
                acc[c][1] = __builtin_amdgcn_mfma_f32_16x16x32_bf16(xf[1], w, acc[c][1], 0, 0, 0);
            }
        }
        #pragma unroll
        for (int c = 0; c < 4; ++c) {
            const float bia = (c < 2) ? bf_[c * 16 + l15] : bg_[(c - 2) * 16 + l15];
            __bf16* dst = (c < 2) ? fbuf : gbuf;
            const int ch = (c & 1) * 16 + l15;
            #pragma unroll
            for (int rb = 0; rb < 2; ++rb)
                #pragma unroll
                for (int r = 0; r < 4; ++r)
                    dst[(size_t)(rowbase + (rb0 + rb) * 16 + lhi * 4 + r) * CK + ch] =
                        (__bf16)(acc[c][rb][r] + bia);
        }
    } else {
        // h channels, swapped operands -> hT directly
        const int nct = (wv < 6) ? 3 : 2;
        const int ct0 = (wv < 6) ? (wv - 2) * 3 : 12 + (wv - 6) * 2;
        f32x4 acc[3][4];
        #pragma unroll
        for (int c = 0; c < 3; ++c)
            #pragma unroll
            for (int rb = 0; rb < 4; ++rb) acc[c][rb] = (f32x4){0.f, 0.f, 0.f, 0.f};
        #pragma unroll
        for (int kk = 0; kk < 8; ++kk) {
            bf16x8 xf[4];
            #pragma unroll
            for (int rb = 0; rb < 4; ++rb) {
                const int row = rb * 16 + l15;
                xf[rb] = *(const bf16x8*)&xs[row * 256 + (((kk * 4 + lhi) ^ (row & 7)) * 8)];
            }
            #pragma unroll
            for (int c = 0; c < 3; ++c) {
                if (c < nct) {
                    const bf16x8 w = *(const bf16x8*)
                        &WTf[((size_t)((4 + ct0 + c) * 8 + kk) * 16 + l15) * 32 + lhi * 8];
                    #pragma unroll
                    for (int rb = 0; rb < 4; ++rb)
                        acc[c][rb] = __builtin_amdgcn_mfma_f32_16x16x32_bf16(w, xf[rb], acc[c][rb], 0, 0, 0);
                }
            }
        }
        #pragma unroll
        for (int c = 0; c < 3; ++c) {
            if (c < nct) {
                #pragma unroll
                for (int r = 0; r < 4; ++r) {
                    const int ch = (ct0 + c) * 16 + lhi * 4 + r;
                    const float bia = bh_[ch];
                    #pragma unroll
                    for (int rb = 0; rb < 4; ++rb)
                        hT[((size_t)b * CDIM + ch) * NPIX + nloc + rb * 16 + l15] =
                            (__bf16)(acc[c][rb][r] + bia);
                }
            }
        }
    }
}

// ---------------- attention ----------------
// Per tile (64 kv):
//  S-waves (wv<4, q-block wv): S^T = mfma(f_frag, g_frag, C=-30) -> lane holds
//  P^T[kv=cb*16+lhi*4+r][q=l15]; exp; cvt_pk packs to dwords u[cb] = (dw0: kv+0,+1; dw1: +2,+3).
//  In-register transpose to A-frag layout (lane holds P[q=l15][kv=lhi*8+j]):
//    stage1 (lane^32): pl32(u0,u2), pl32(u1,u3), pl32(u4,u6), pl32(u5,u7)
//    stage2 (lane^16): pl16(u0,u2), pl16(u1,u3), pl16(u4,u6), pl16(u5,u7)
//    pa0 = {u0,u1,u2,u3}, pa1 = {u4,u5,u6,u7}   (kv 0..31 / 32..63)
//  Write pa to pbuf fragment-linear (uint4 per lane, zero conflicts); barrier;
//  all 8 waves read A-frags + PV-MFMA into their d-slice (uneven split 4x16d + 4x48d).
#define PL32(a, b) asm("v_permlane32_swap_b32 %0, %1" : "+v"(a), "+v"(b))
#define PL16(a, b) asm("v_permlane16_swap_b32 %0, %1" : "+v"(a), "+v"(b))

#define ATTN_TILE(KV, PB, FC, FN, HC, HN)                                           \
do {                                                                                \
    if (wv < 4) {                                                                   \
        const f32x4 m30 = {-30.f, -30.f, -30.f, -30.f};                             \
        f32x4 s0 = __builtin_amdgcn_mfma_f32_16x16x32_bf16(FC[0], ga, m30, 0, 0, 0);\
        f32x4 s1 = __builtin_amdgcn_mfma_f32_16x16x32_bf16(FC[1], ga, m30, 0, 0, 0);\
        f32x4 s2 = __builtin_amdgcn_mfma_f32_16x16x32_bf16(FC[2], ga, m30, 0, 0, 0);\
        f32x4 s3 = __builtin_amdgcn_mfma_f32_16x16x32_bf16(FC[3], ga, m30, 0, 0, 0);\
        {   /* prefetch next f tile */                                              \
            const size_t ko = (size_t)((KV) + 64) * CK;                             \
            FN[0] = *(const bf16x8*)(fp + ko);                                      \
            FN[1] = *(const bf16x8*)(fp + ko + 16 * CK);                            \
            FN[2] = *(const bf16x8*)(fp + ko + 32 * CK);                            \
            FN[3] = *(const bf16x8*)(fp + ko + 48 * CK);                            \
        }                                                                           \
        float p0 = __expf(s0[0]), p1 = __expf(s0[1]), p2 = __expf(s0[2]), p3 = __expf(s0[3]); \
        float p4 = __expf(s1[0]), p5 = __expf(s1[1]), p6 = __expf(s1[2]), p7 = __expf(s1[3]); \
        float p8 = __expf(s2[0]), p9 = __expf(s2[1]), pa_ = __expf(s2[2]), pb_ = __expf(s2[3]); \
        float pc_ = __expf(s3[0]), pd_ = __expf(s3[1]), pe_ = __expf(s3[2]), pf_ = __expf(s3[3]); \
        lsum += ((p0 + p1) + (p2 + p3)) + ((p4 + p5) + (p6 + p7))                   \
              + ((p8 + p9) + (pa_ + pb_)) + ((pc_ + pd_) + (pe_ + pf_));            \
        unsigned int u0 = cvtpk(p0, p1), u1 = cvtpk(p2, p3);                        \
        unsigned int u2 = cvtpk(p4, p5), u3 = cvtpk(p6, p7);                        \
        unsigned int u4 = cvtpk(p8, p9), u5 = cvtpk(pa_, pb_);                      \
        unsigned int u6 = cvtpk(pc_, pd_), u7 = cvtpk(pe_, pf_);                    \
        PL32(u0, u2); PL32(u1, u3); PL32(u4, u6); PL32(u5, u7);                     \
        PL16(u0, u2); PL16(u1, u3); PL16(u4, u6); PL16(u5, u7);                     \
        uint4 w0; w0.x = u0; w0.y = u1; w0.z = u2; w0.w = u3;                       \
        uint4 w1; w1.x = u4; w1.y = u5; w1.z = u6; w1.w = u7;                       \
        pbuf[PB][wv * 2 + 0][lane] = w0;                                            \
        pbuf[PB][wv * 2 + 1][lane] = w1;                                            \
    }                                                                               \
    __syncthreads();                                                                \
    {   /* prefetch next H tile */                                                  \
        const size_t kn = (size_t)((KV) + 64);                                      \
        HN[0] = *(const bf16x8*)(hp + kn);                                          \
        HN[1] = *(const bf16x8*)(hp + kn + 32);                                     \
        if (wv >= 4) {                                                              \
            HN[2] = *(const bf16x8*)(hp + (size_t)16 * NPIX + kn);                  \
            HN[3] = *(const bf16x8*)(hp + (size_t)16 * NPIX + kn + 32);             \
            HN[4] = *(const bf16x8*)(hp + (size_t)32 * NPIX + kn);                  \
            HN[5] = *(const bf16x8*)(hp + (size_t)32 * NPIX + kn + 32);             \
        }                                                                           \
    }                                                                               \
    __builtin_amdgcn_s_setprio(1);                                                  \
    _Pragma("unroll")                                                               \
    for (int rt = 0; rt < 4; ++rt) {                                                \
        U128 A0, A1;                                                                \
        A0.u4 = pbuf[PB][rt * 2 + 0][lane];                                         \
        A1.u4 = pbuf[PB][rt * 2 + 1][lane];                                         \
        O_[rt][0] = __builtin_amdgcn_mfma_f32_16x16x32_bf16(A0.v, HC[0], O_[rt][0], 0, 0, 0); \
        O_[rt][0] = __builtin_amdgcn_mfma_f32_16x16x32_bf16(A1.v, HC[1], O_[rt][0], 0, 0, 0); \
        if (wv >= 4) {                                                              \
            O_[rt][1] = __builtin_amdgcn_mfma_f32_16x16x32_bf16(A0.v, HC[2], O_[rt][1], 0, 0, 0); \
            O_[rt][1] = __builtin_amdgcn_mfma_f32_16x16x32_bf16(A1.v, HC[3], O_[rt][1], 0, 0, 0); \
            O_[rt][2] = __builtin_amdgcn_mfma_f32_16x16x32_bf16(A0.v, HC[4], O_[rt][2], 0, 0, 0); \
            O_[rt][2] = __builtin_amdgcn_mfma_f32_16x16x32_bf16(A1.v, HC[5], O_[rt][2], 0, 0, 0); \
        }                                                                           \
    }                                                                               \
    __builtin_amdgcn_s_setprio(0);                                                  \
} while (0)

__global__ __launch_bounds__(512, 1) void attn_kernel(
    const __bf16* __restrict__ fbuf, const __bf16* __restrict__ gbuf,
    const __bf16* __restrict__ hT, const float* __restrict__ x,
    const float* __restrict__ gamma_p, float* __restrict__ out)
{
    __shared__ uint4 pbuf[2][8][64];     // 16 KB, fragment-linear P (zero-conflict)
    __shared__ float lbuf[64];

    const int t = threadIdx.x;
    const int lane = t & 63;
    const int wv = t >> 6;
    const int l15 = lane & 15;
    const int lhi = lane >> 4;

    // XCD swizzle: batch b's 64 blocks -> XCDs {2b,2b+1}
    const int xcd = blockIdx.x & 7;
    const int b = xcd >> 1;
    const int qt = ((blockIdx.x >> 3) << 1) + (xcd & 1);
    const int q0 = qt * 64;

    const __bf16* fb = fbuf + (size_t)b * NPIX * CK;
    const __bf16* hb = hT + (size_t)b * CDIM * NPIX;

    // uneven d-split: S-waves own 16 d, big waves own 48 d
    const int dbase = (wv < 4) ? wv * 16 : 64 + (wv - 4) * 48;
    const __bf16* hp = hb + (size_t)(dbase + l15) * NPIX + lhi * 8;
    const __bf16* fp = fb + (size_t)l15 * CK + lhi * 8;   // + kv*CK + cb*16*CK

    bf16x8 ga = {};
    if (wv < 4)
        ga = *(const bf16x8*)&gbuf[((size_t)b * NPIX + q0 + wv * 16 + l15) * CK + lhi * 8];

    f32x4 O_[4][3];
    #pragma unroll
    for (int i = 0; i < 4; ++i)
        #pragma unroll
        for (int j = 0; j < 3; ++j) O_[i][j] = (f32x4){0.f, 0.f, 0.f, 0.f};
    float lsum = 0.f;

    bf16x8 FA[4], FB[4], HA[6], HB[6];

    // prologue: tile 0 operands
    if (wv < 4) {
        FA[0] = *(const bf16x8*)(fp);
        FA[1] = *(const bf16x8*)(fp + 16 * CK);
        FA[2] = *(const bf16x8*)(fp + 32 * CK);
        FA[3] = *(const bf16x8*)(fp + 48 * CK);
    }
    HA[0] = *(const bf16x8*)(hp);
    HA[1] = *(const bf16x8*)(hp + 32);
    if (wv >= 4) {
        HA[2] = *(const bf16x8*)(hp + (size_t)16 * NPIX);
        HA[3] = *(const bf16x8*)(hp + (size_t)16 * NPIX + 32);
        HA[4] = *(const bf16x8*)(hp + (size_t)32 * NPIX);
        HA[5] = *(const bf16x8*)(hp + (size_t)32 * NPIX + 32);
    }

    for (int it = 0; it < 32; ++it) {
        const int kv = it * 128;
        ATTN_TILE(kv,      0, FA, FB, HA, HB);
        ATTN_TILE(kv + 64, 1, FB, FA, HB, HA);
    }

    // epilogue: lsum reduce (per q = l15 within S-wave), share, write out
    if (wv < 4) {
        lsum += __shfl_xor(lsum, 16, 64);
        lsum += __shfl_xor(lsum, 32, 64);
        if (lane < 16) lbuf[wv * 16 + l15] = lsum;
    }
    __syncthreads();

    const float gm = gamma_p[0];
    #pragma unroll
    for (int rt = 0; rt < 4; ++rt) {
        #pragma unroll
        for (int r = 0; r < 4; ++r) {
            const int row = rt * 16 + lhi * 4 + r;
            const float rl = gm / lbuf[row];
            const size_t base = ((size_t)b * NPIX + q0 + row) * CDIM + dbase;
            out[base + l15] = fmaf(rl, O_[rt][0][r], x[base + l15]);
            if (wv >= 4) {
                out[base + 16 + l15] = fmaf(rl, O_[rt][1][r], x[base + 16 + l15]);
                out[base + 32 + l15] = fmaf(rl, O_[rt][2][r], x[base + 32 + l15]);
            }
        }
    }
}

extern "C" void kernel_launch(void* const* d_in, const int* in_sizes, int n_in,
                              void* d_out, int out_size, void* d_ws, size_t ws_size,
                              hipStream_t stream)
{
    const float* x     = (const float*)d_in[0];
    const float* Wf    = (const float*)d_in[1];
    const float* bf    = (const float*)d_in[2];
    const float* Wg    = (const float*)d_in[3];
    const float* bg    = (const float*)d_in[4];
    const float* Wh    = (const float*)d_in[5];
    const float* bh    = (const float*)d_in[6];
    const float* gamma = (const float*)d_in[7];
    float* out = (float*)d_out;

    // workspace: f (1MB) | g (1MB) | hT (8MB) | WTf (160KB), all bf16
    __bf16* fbuf = (__bf16*)d_ws;
    __bf16* gbuf = fbuf + (size_t)4 * NPIX * CK;
    __bf16* hT   = gbuf + (size_t)4 * NPIX * CK;
    __bf16* WTf  = hT + (size_t)4 * CDIM * NPIX;

    prep_wtf<<<256, 256, 0, stream>>>(Wf, Wg, Wh, WTf);
    proj_mfma<<<256, 512, 0, stream>>>(x, WTf, bf, bg, bh, fbuf, gbuf, hT);
    attn_kernel<<<256, 512, 0, stream>>>(fbuf, gbuf, hT, x, gamma, out);
}